// Round 4
// baseline (16724.187 us; speedup 1.0000x reference)
//
#include <hip/hip_runtime.h>

#define B_    32
#define SSRC  128
#define STGT  64
#define E_    256
#define H_    512
#define G4    2048
#define V_    32000

typedef unsigned short u16;
typedef short bf16x8 __attribute__((ext_vector_type(8)));
typedef float f32x4 __attribute__((ext_vector_type(4)));

__device__ __forceinline__ u16 f2b(float f) {
  unsigned u = __float_as_uint(f);
  u += 0x7FFFu + ((u >> 16) & 1u);
  return (u16)(u >> 16);
}
__device__ __forceinline__ float b2f(u16 h) {
  return __uint_as_float(((unsigned)h) << 16);
}
__device__ __forceinline__ float sigm(float x) { return 1.0f / (1.0f + __expf(-x)); }
__device__ __forceinline__ float tanh_(float x) { return 1.0f - 2.0f / (1.0f + __expf(2.0f * x)); }

// ---- packed bf16x2 dot product: acc += a.lo*b.lo + a.hi*b.hi ----
#if defined(__has_builtin)
#if __has_builtin(__builtin_amdgcn_fdot2_f32_bf16)
#define HAS_DOT2 1
#endif
#endif

#ifdef HAS_DOT2
typedef __bf16 b162 __attribute__((ext_vector_type(2)));
__device__ __forceinline__ float dot2u(unsigned a, unsigned b, float acc) {
  return __builtin_amdgcn_fdot2_f32_bf16(__builtin_bit_cast(b162, a),
                                         __builtin_bit_cast(b162, b), acc, false);
}
#else
__device__ __forceinline__ float dot2u(unsigned a, unsigned b, float acc) {
  acc += __uint_as_float(a << 16) * __uint_as_float(b << 16);
  acc += __uint_as_float(a & 0xffff0000u) * __uint_as_float(b & 0xffff0000u);
  return acc;
}
#endif

__device__ __forceinline__ void loadw8(uint4* buf, const u16* Wrow, int coff) {
  const uint4* wp = (const uint4*)Wrow + coff;
#pragma unroll
  for (int i = 0; i < 8; ++i) buf[i] = wp[i];
}
__device__ __forceinline__ float dotrow(const uint4* wv, const uint4* hv) {
  float acc = 0.f;
#pragma unroll
  for (int i = 0; i < 8; ++i) {
    acc = dot2u(wv[i].x, hv[i].x, acc);
    acc = dot2u(wv[i].y, hv[i].y, acc);
    acc = dot2u(wv[i].z, hv[i].z, acc);
    acc = dot2u(wv[i].w, hv[i].w, acc);
  }
  return acc;
}
__device__ __forceinline__ float red8(float acc) {
  acc += __shfl_xor(acc, 1);
  acc += __shfl_xor(acc, 2);
  acc += __shfl_xor(acc, 4);
  return acc;
}

// ---------------- prep: gathers + bf16 conversions ----------------
__global__ void prep_kernel(const int* __restrict__ src, const int* __restrict__ tgt,
                            const float* __restrict__ enc_emb, const float* __restrict__ dec_emb,
                            const float* __restrict__ enc_Wih, const float* __restrict__ dec_Wih,
                            const float* __restrict__ out_W,
                            const float* __restrict__ enc_Whh, const float* __restrict__ dec_Whh,
                            const float* __restrict__ attn_W,
                            u16* __restrict__ A_enc, u16* __restrict__ A_dec,
                            u16* __restrict__ WihE, u16* __restrict__ WihD,
                            u16* __restrict__ outWb,
                            u16* __restrict__ WhhEb, u16* __restrict__ WhhDb,
                            u16* __restrict__ WihCb, u16* __restrict__ Whb, u16* __restrict__ Web)
{
  const long n_outw = (long)V_ * H_;
  const long n_aenc = (long)B_ * SSRC * E_;
  const long n_adec = (long)B_ * STGT * E_;
  const long n_wih  = (long)G4 * E_;
  const long n_whh  = (long)G4 * H_;
  const long n_att  = (long)H_ * H_;
  const long total = n_outw + n_aenc + n_adec + 2 * n_wih + 3 * n_whh + 2 * n_att;
  for (long i = (long)blockIdx.x * blockDim.x + threadIdx.x; i < total;
       i += (long)gridDim.x * blockDim.x) {
    long x = i;
    if (x < n_outw) { outWb[x] = f2b(out_W[x]); continue; }
    x -= n_outw;
    if (x < n_aenc) {
      int row = (int)(x >> 8), e = (int)(x & 255);
      A_enc[x] = f2b(enc_emb[(size_t)src[row] * E_ + e]);
      continue;
    }
    x -= n_aenc;
    if (x < n_adec) {
      int row = (int)(x >> 8), e = (int)(x & 255);
      A_dec[x] = f2b(dec_emb[(size_t)tgt[row] * E_ + e]);
      continue;
    }
    x -= n_adec;
    if (x < n_wih) { WihE[x] = f2b(enc_Wih[x]); continue; }
    x -= n_wih;
    if (x < n_wih) {
      int r = (int)(x >> 8), e = (int)(x & 255);
      WihD[x] = f2b(dec_Wih[(size_t)r * 768 + e]);
      continue;
    }
    x -= n_wih;
    if (x < n_whh) { WhhEb[x] = f2b(enc_Whh[x]); continue; }
    x -= n_whh;
    if (x < n_whh) { WhhDb[x] = f2b(dec_Whh[x]); continue; }
    x -= n_whh;
    if (x < n_whh) {
      int r = (int)(x >> 9), k = (int)(x & 511);
      WihCb[x] = f2b(dec_Wih[(size_t)r * 768 + 256 + k]);
      continue;
    }
    x -= n_whh;
    if (x < n_att) {
      int d = (int)(x >> 9), k = (int)(x & 511);
      Whb[x] = f2b(attn_W[(size_t)d * 1024 + k]);
      continue;
    }
    x -= n_att;
    {
      int d = (int)(x >> 9), k = (int)(x & 511);
      Web[x] = f2b(attn_W[(size_t)d * 1024 + 512 + k]);
    }
  }
}

// ---------------- NT GEMM: C[m][n] = sum_k A[m][k]*B[n][k] + bias[n] ----------------
template<int KTOT, bool OBF>
__global__ __launch_bounds__(256, 2) void gemm_nt(
    const u16* __restrict__ A, const u16* __restrict__ Bm,
    const float* __restrict__ bias, void* __restrict__ Cv, int M, int N)
{
  int nbm = M >> 7;
  int bn = blockIdx.x / nbm;
  int bm = blockIdx.x % nbm;
  int w = threadIdx.x >> 6, l = threadIdx.x & 63;
  int wr = w >> 1, wc = w & 1;
  int m0 = bm * 128 + wr * 64, n0 = bn * 128 + wc * 64;
  int lr = l & 15, ko = (l >> 4) * 8;
  f32x4 acc[4][4] = {};
  const u16* Ap = A + (size_t)(m0 + lr) * KTOT + ko;
  const u16* Bp = Bm + (size_t)(n0 + lr) * KTOT + ko;
  for (int k0 = 0; k0 < KTOT; k0 += 32) {
    bf16x8 af[4], bfr[4];
#pragma unroll
    for (int i = 0; i < 4; ++i) af[i] = *(const bf16x8*)(Ap + (size_t)i * 16 * KTOT + k0);
#pragma unroll
    for (int i = 0; i < 4; ++i) bfr[i] = *(const bf16x8*)(Bp + (size_t)i * 16 * KTOT + k0);
#pragma unroll
    for (int i = 0; i < 4; ++i)
#pragma unroll
      for (int j = 0; j < 4; ++j)
        acc[i][j] = __builtin_amdgcn_mfma_f32_16x16x32_bf16(af[i], bfr[j], acc[i][j], 0, 0, 0);
  }
  int rbase = (l >> 4) * 4;
#pragma unroll
  for (int i = 0; i < 4; ++i) {
#pragma unroll
    for (int j = 0; j < 4; ++j) {
      int gn = n0 + j * 16 + lr;
      float bv = bias ? bias[gn] : 0.f;
#pragma unroll
      for (int r = 0; r < 4; ++r) {
        int gm = m0 + i * 16 + rbase + r;
        float v = acc[i][j][r] + bv;
        if (OBF) ((u16*)Cv)[(size_t)gm * N + gn] = f2b(v);
        else     ((float*)Cv)[(size_t)gm * N + gn] = v;
      }
    }
  }
}

// ---------------- encoder: one block per batch row, zero cross-block sync ----------
__global__ __launch_bounds__(512) void encoder_kernel(
    const u16* __restrict__ Whh, const u16* __restrict__ encXW,
    u16* __restrict__ eo_g, u16* __restrict__ hfin, float* __restrict__ cfin)
{
  const int b = blockIdx.x;
  const int tid = threadIdx.x;
  __shared__ float zS[G4];
  __shared__ float cS[H_];
  __shared__ __align__(16) u16 h16[H_];
  cS[tid & 511] = 0.f;
  h16[tid & 511] = 0;
  __syncthreads();
  const int w = tid >> 6, l = tid & 63, r = l >> 3, c = l & 7;
  const int coff = c << 3;

  for (int t = 0; t < SSRC; ++t) {
    // ---- z = Whh @ h (2048 rows), h chunk in regs, dual-buffered weight stream ----
    {
      uint4 hv[8];
      const uint4* hp = (const uint4*)h16 + coff;
#pragma unroll
      for (int i = 0; i < 8; ++i) hv[i] = hp[i];
      uint4 wa[8], wb[8];
      loadw8(wa, Whh + ((size_t)((w << 8) + r)) * H_, coff);
#pragma unroll 1
      for (int it = 0; it < 32; it += 2) {
        loadw8(wb, Whh + ((size_t)((w << 8) + ((it + 1) << 3) + r)) * H_, coff);
        {
          float acc = red8(dotrow(wa, hv));
          if (c == 0) zS[(w << 8) + (it << 3) + r] = acc;
        }
        loadw8(wa, Whh + ((size_t)((w << 8) + ((it + 2) << 3) + r)) * H_, coff);
        {
          float acc = red8(dotrow(wb, hv));
          if (c == 0) zS[(w << 8) + ((it + 1) << 3) + r] = acc;
        }
      }
    }
    __syncthreads();
    // ---- gates ----
    {
      const u16* xr = encXW + ((size_t)b * SSRC + t) * G4;
      int j = tid;
      float iv = zS[j]        + b2f(xr[j]);
      float fv = zS[512 + j]  + b2f(xr[512 + j]);
      float gv = zS[1024 + j] + b2f(xr[1024 + j]);
      float ov = zS[1536 + j] + b2f(xr[1536 + j]);
      float cn = sigm(fv) * cS[j] + sigm(iv) * tanh_(gv);
      float hn = sigm(ov) * tanh_(cn);
      cS[j] = cn;
      u16 hb = f2b(hn);
      h16[j] = hb;
      eo_g[((size_t)b * SSRC + t) * H_ + j] = hb;
    }
    __syncthreads();
  }
  hfin[(size_t)b * H_ + tid] = h16[tid];
  cfin[(size_t)b * H_ + tid] = cS[tid];
}

// ---------------- decoder: one block per batch row -------------------------------
__global__ __launch_bounds__(512) void decoder_kernel(
    const u16* __restrict__ Whh, const u16* __restrict__ WihC,
    const u16* __restrict__ Whb, const u16* __restrict__ eprojb,
    const u16* __restrict__ decXW, const u16* __restrict__ eo_g,
    const u16* __restrict__ hfin, const float* __restrict__ cfin,
    const float* __restrict__ attn_b, const float* __restrict__ attn_v,
    u16* __restrict__ dech)
{
  const int b = blockIdx.x;
  const int tid = threadIdx.x;
  __shared__ __align__(16) u16 eo16[SSRC * H_];   // 128 KB, row's enc_out
  __shared__ float zS[G4];
  __shared__ __align__(16) float qS[H_];
  __shared__ float cS[H_];
  __shared__ float bS[H_];
  __shared__ __align__(16) float vS[H_];
  __shared__ __align__(16) u16 h16[H_];
  __shared__ __align__(16) u16 ctx16[H_];
  __shared__ float scoreS[SSRC];
  __shared__ float aS[SSRC];

  {
    const uint4* srcp = (const uint4*)(eo_g + (size_t)b * SSRC * H_);
    uint4* dst = (uint4*)eo16;
    for (int i = tid; i < SSRC * H_ / 8; i += 512) dst[i] = srcp[i];
    h16[tid] = hfin[(size_t)b * H_ + tid];
    cS[tid] = cfin[(size_t)b * H_ + tid];
    bS[tid] = attn_b[tid];
    vS[tid] = attn_v[tid];
  }
  __syncthreads();
  const int w = tid >> 6, l = tid & 63, r = l >> 3, c = l & 7;
  const int coff = c << 3;

  for (int t = 0; t < STGT; ++t) {
    // ---- q = W_h @ h + attn_b (512 rows) ----
    {
      uint4 hv[8];
      const uint4* hp = (const uint4*)h16 + coff;
#pragma unroll
      for (int i = 0; i < 8; ++i) hv[i] = hp[i];
      uint4 wa[8], wb[8];
      loadw8(wa, Whb + ((size_t)((w << 6) + r)) * H_, coff);
#pragma unroll 1
      for (int it = 0; it < 8; it += 2) {
        loadw8(wb, Whb + ((size_t)((w << 6) + ((it + 1) << 3) + r)) * H_, coff);
        {
          float acc = red8(dotrow(wa, hv));
          int j = (w << 6) + (it << 3) + r;
          if (c == 0) qS[j] = acc + bS[j];
        }
        loadw8(wa, Whb + ((size_t)((w << 6) + ((it + 2) << 3) + r)) * H_, coff);
        {
          float acc = red8(dotrow(wb, hv));
          int j = (w << 6) + ((it + 1) << 3) + r;
          if (c == 0) qS[j] = acc + bS[j];
        }
      }
    }
    __syncthreads();
    // ---- energy + score: s = tid>>2, 4 lanes x 128 d each ----
    {
      int s = tid >> 2, qt = tid & 3, d0 = qt << 7;
      const uint4* ep = (const uint4*)(eprojb + ((size_t)b * SSRC + s) * H_ + d0);
      float acc = 0.f;
#pragma unroll 4
      for (int i = 0; i < 16; ++i) {
        uint4 ev = ep[i];
        int d = d0 + (i << 3);
        float4 q0 = *(const float4*)(qS + d);
        float4 q1 = *(const float4*)(qS + d + 4);
        float4 v0 = *(const float4*)(vS + d);
        float4 v1 = *(const float4*)(vS + d + 4);
        acc += v0.x * tanh_(b2f((u16)(ev.x & 0xffff)) + q0.x);
        acc += v0.y * tanh_(b2f((u16)(ev.x >> 16))    + q0.y);
        acc += v0.z * tanh_(b2f((u16)(ev.y & 0xffff)) + q0.z);
        acc += v0.w * tanh_(b2f((u16)(ev.y >> 16))    + q0.w);
        acc += v1.x * tanh_(b2f((u16)(ev.z & 0xffff)) + q1.x);
        acc += v1.y * tanh_(b2f((u16)(ev.z >> 16))    + q1.y);
        acc += v1.z * tanh_(b2f((u16)(ev.w & 0xffff)) + q1.z);
        acc += v1.w * tanh_(b2f((u16)(ev.w >> 16))    + q1.w);
      }
      acc += __shfl_xor(acc, 1);
      acc += __shfl_xor(acc, 2);
      if (qt == 0) scoreS[s] = acc;
    }
    __syncthreads();
    // ---- softmax over 128 (wave 0) ----
    if (tid < 64) {
      float s1 = scoreS[tid], s2 = scoreS[64 + tid];
      float m = fmaxf(s1, s2);
#pragma unroll
      for (int off = 32; off; off >>= 1) m = fmaxf(m, __shfl_xor(m, off));
      float e1 = __expf(s1 - m), e2 = __expf(s2 - m);
      float sm = e1 + e2;
#pragma unroll
      for (int off = 32; off; off >>= 1) sm += __shfl_xor(sm, off);
      float inv = 1.0f / sm;
      aS[tid] = e1 * inv;
      aS[64 + tid] = e2 * inv;
    }
    __syncthreads();
    // ---- context: 256 threads x 2 d each ----
    if (tid < 256) {
      const unsigned* eoU = (const unsigned*)eo16;
      float a0 = 0.f, a1 = 0.f;
#pragma unroll 4
      for (int s = 0; s < SSRC; ++s) {
        unsigned u = eoU[(s << 8) + tid];
        float as = aS[s];
        a0 += as * __uint_as_float(u << 16);
        a1 += as * __uint_as_float(u & 0xffff0000u);
      }
      ((unsigned*)ctx16)[tid] = (unsigned)f2b(a0) | (((unsigned)f2b(a1)) << 16);
    }
    __syncthreads();
    // ---- z = Whh @ h + WihC @ ctx (2048 rows) ----
    {
      uint4 hv[8], xv[8];
      const uint4* hp = (const uint4*)h16 + coff;
      const uint4* xp = (const uint4*)ctx16 + coff;
#pragma unroll
      for (int i = 0; i < 8; ++i) { hv[i] = hp[i]; xv[i] = xp[i]; }
      uint4 wa[8], wb[8], xa[8], xb[8];
      loadw8(wa, Whh + ((size_t)((w << 8) + r)) * H_, coff);
      loadw8(xa, WihC + ((size_t)((w << 8) + r)) * H_, coff);
#pragma unroll 1
      for (int it = 0; it < 32; it += 2) {
        loadw8(wb, Whh + ((size_t)((w << 8) + ((it + 1) << 3) + r)) * H_, coff);
        loadw8(xb, WihC + ((size_t)((w << 8) + ((it + 1) << 3) + r)) * H_, coff);
        {
          float acc = dotrow(wa, hv);
          acc += dotrow(xa, xv);
          acc = red8(acc);
          if (c == 0) zS[(w << 8) + (it << 3) + r] = acc;
        }
        loadw8(wa, Whh + ((size_t)((w << 8) + ((it + 2) << 3) + r)) * H_, coff);
        loadw8(xa, WihC + ((size_t)((w << 8) + ((it + 2) << 3) + r)) * H_, coff);
        {
          float acc = dotrow(wb, hv);
          acc += dotrow(xb, xv);
          acc = red8(acc);
          if (c == 0) zS[(w << 8) + ((it + 1) << 3) + r] = acc;
        }
      }
    }
    __syncthreads();
    // ---- gates ----
    {
      const u16* xr = decXW + ((size_t)b * STGT + t) * G4;
      int j = tid;
      float iv = zS[j]        + b2f(xr[j]);
      float fv = zS[512 + j]  + b2f(xr[512 + j]);
      float gv = zS[1024 + j] + b2f(xr[1024 + j]);
      float ov = zS[1536 + j] + b2f(xr[1536 + j]);
      float cn = sigm(fv) * cS[j] + sigm(iv) * tanh_(gv);
      float hn = sigm(ov) * tanh_(cn);
      cS[j] = cn;
      u16 hb = f2b(hn);
      h16[j] = hb;
      dech[((size_t)b * STGT + t) * H_ + j] = hb;
    }
    __syncthreads();
  }
}

// ---------------- workspace layout (bytes) ----------------
#define OFF_HFIN   0u            //  32 KB u16 [32][512]
#define OFF_CFIN   32768u        //  64 KB f32 [32][512]
#define OFF_WHHE   131072u       //  2.10 MB
#define OFF_WHHD   2228224u      //  2.10 MB
#define OFF_WIHC   4325376u      //  2.10 MB
#define OFF_WHB    6422528u      //  0.52 MB
#define OFF_WEB    6946816u      //  0.52 MB
#define OFF_AENC   7471104u      //  2.10 MB  [dead after gemm1] -> aliased by EPROJ
#define OFF_ADEC   9568256u      //  1.05 MB  [dead after gemm2]
#define OFF_WIHE   10616832u     //  1.05 MB  [dead after gemm1]
#define OFF_WIHD   11665408u     //  1.05 MB  [dead after gemm2]
#define OFF_OUTW   12713984u     // 32.77 MB
#define OFF_ENCXW  45481984u     // 16.78 MB
#define OFF_DECXW  62259200u     //  8.39 MB
#define OFF_EO     70647808u     //  4.19 MB
#define OFF_EPROJ  OFF_AENC      //  4.19 MB (written after A_enc/WihE dead)
#define OFF_DECH   74842112u     //  2.10 MB  -> end 76.94 MB

extern "C" void kernel_launch(void* const* d_in, const int* in_sizes, int n_in,
                              void* d_out, int out_size, void* d_ws, size_t ws_size,
                              hipStream_t stream)
{
  const int*   src     = (const int*)d_in[0];
  const int*   tgt     = (const int*)d_in[1];
  const float* enc_emb = (const float*)d_in[2];
  const float* enc_Wih = (const float*)d_in[3];
  const float* enc_Whh = (const float*)d_in[4];
  const float* enc_b   = (const float*)d_in[5];
  const float* attn_W  = (const float*)d_in[6];
  const float* attn_b  = (const float*)d_in[7];
  const float* attn_v  = (const float*)d_in[8];
  const float* dec_emb = (const float*)d_in[9];
  const float* dec_Wih = (const float*)d_in[10];
  const float* dec_Whh = (const float*)d_in[11];
  const float* dec_b   = (const float*)d_in[12];
  const float* out_W   = (const float*)d_in[13];
  const float* out_b   = (const float*)d_in[14];

  char* ws = (char*)d_ws;
  u16*   hfin   = (u16*)(ws + OFF_HFIN);
  float* cfin   = (float*)(ws + OFF_CFIN);
  u16*   WhhEb  = (u16*)(ws + OFF_WHHE);
  u16*   WhhDb  = (u16*)(ws + OFF_WHHD);
  u16*   WihCb  = (u16*)(ws + OFF_WIHC);
  u16*   Whb    = (u16*)(ws + OFF_WHB);
  u16*   Web    = (u16*)(ws + OFF_WEB);
  u16*   A_enc  = (u16*)(ws + OFF_AENC);
  u16*   A_dec  = (u16*)(ws + OFF_ADEC);
  u16*   WihE   = (u16*)(ws + OFF_WIHE);
  u16*   WihD   = (u16*)(ws + OFF_WIHD);
  u16*   outWb  = (u16*)(ws + OFF_OUTW);
  u16*   encXW  = (u16*)(ws + OFF_ENCXW);
  u16*   decXW  = (u16*)(ws + OFF_DECXW);
  u16*   eo_g   = (u16*)(ws + OFF_EO);
  u16*   eprojb = (u16*)(ws + OFF_EPROJ);
  u16*   dech   = (u16*)(ws + OFF_DECH);

  prep_kernel<<<2048, 256, 0, stream>>>(src, tgt, enc_emb, dec_emb, enc_Wih, dec_Wih, out_W,
                                        enc_Whh, dec_Whh, attn_W,
                                        A_enc, A_dec, WihE, WihD, outWb,
                                        WhhEb, WhhDb, WihCb, Whb, Web);

  // encXW = emb_src @ enc_Wih^T + enc_b   (M=4096, N=2048, K=256) -> bf16
  gemm_nt<256, true><<<512, 256, 0, stream>>>(A_enc, WihE, enc_b, (void*)encXW, 4096, 2048);
  // decXW = emb_tgt @ dec_Wih[:, :E]^T + dec_b  (M=2048, N=2048, K=256) -> bf16
  gemm_nt<256, true><<<256, 256, 0, stream>>>(A_dec, WihD, dec_b, (void*)decXW, 2048, 2048);

  // encoder recurrence: 32 independent blocks
  encoder_kernel<<<32, 512, 0, stream>>>(WhhEb, encXW, eo_g, hfin, cfin);

  // enc_proj = enc_out @ W_e^T  (M=4096, N=512, K=512) -> bf16, no bias
  gemm_nt<512, true><<<128, 256, 0, stream>>>(eo_g, Web, nullptr, (void*)eprojb, 4096, 512);

  // decoder recurrence: 32 independent blocks
  decoder_kernel<<<32, 512, 0, stream>>>(WhhDb, WihCb, Whb, eprojb, decXW, eo_g,
                                         hfin, cfin, attn_b, attn_v, dech);

  // out = dec_h @ out_W^T + out_b  (M=2048, N=32000, K=512) -> f32
  gemm_nt<512, false><<<4000, 256, 0, stream>>>(dech, outWb, out_b, d_out, 2048, 32000);
}

// Round 5
// 2252.272 us; speedup vs baseline: 7.4255x; 7.4255x over previous
//
#include <hip/hip_runtime.h>

#define B_    32
#define SSRC  128
#define STGT  64
#define E_    256
#define H_    512
#define G4    2048
#define V_    32000

typedef unsigned short u16;
typedef short bf16x8 __attribute__((ext_vector_type(8)));
typedef float f32x4 __attribute__((ext_vector_type(4)));

__device__ __forceinline__ u16 f2b(float f) {
  unsigned u = __float_as_uint(f);
  u += 0x7FFFu + ((u >> 16) & 1u);
  return (u16)(u >> 16);
}
__device__ __forceinline__ float b2f(u16 h) {
  return __uint_as_float(((unsigned)h) << 16);
}
__device__ __forceinline__ float sigm(float x) { return 1.0f / (1.0f + __expf(-x)); }
__device__ __forceinline__ float tanh_(float x) { return 1.0f - 2.0f / (1.0f + __expf(2.0f * x)); }

// ---- packed bf16x2 dot ----
#if defined(__has_builtin)
#if __has_builtin(__builtin_amdgcn_fdot2_f32_bf16)
#define HAS_DOT2 1
#endif
#endif
#ifdef HAS_DOT2
typedef __bf16 b162 __attribute__((ext_vector_type(2)));
__device__ __forceinline__ float dot2u(unsigned a, unsigned b, float acc) {
  return __builtin_amdgcn_fdot2_f32_bf16(__builtin_bit_cast(b162, a),
                                         __builtin_bit_cast(b162, b), acc, false);
}
#else
__device__ __forceinline__ float dot2u(unsigned a, unsigned b, float acc) {
  acc += __uint_as_float(a << 16) * __uint_as_float(b << 16);
  acc += __uint_as_float(a & 0xffff0000u) * __uint_as_float(b & 0xffff0000u);
  return acc;
}
#endif

// ---- device-coherent (cache-bypassing) accesses, no whole-cache maintenance ----
__device__ __forceinline__ uint4 cload4(const void* p) {
  uint4 r;
  asm volatile("global_load_dwordx4 %0, %1, off sc0 sc1\n\ts_waitcnt vmcnt(0)"
               : "=v"(r) : "v"(p) : "memory");
  return r;
}
__device__ __forceinline__ void cstoref(float* p, float v) {
  asm volatile("global_store_dword %0, %1, off sc0 sc1" :: "v"(p), "v"(v) : "memory");
}
__device__ __forceinline__ void cstoreu(unsigned* p, unsigned v) {
  asm volatile("global_store_dword %0, %1, off sc0 sc1" :: "v"(p), "v"(v) : "memory");
}

// ---- group barrier: per-block flag + gang poll, no fences ----
__device__ __forceinline__ void gbar(int* flags, int myid, int target) {
  asm volatile("s_waitcnt vmcnt(0)" ::: "memory");
  __syncthreads();
  if (threadIdx.x == 0)
    __hip_atomic_store(flags + myid, target, __ATOMIC_RELAXED, __HIP_MEMORY_SCOPE_AGENT);
  if (threadIdx.x < 64) {
    int l = threadIdx.x & 31;
    while (__hip_atomic_load(flags + l, __ATOMIC_RELAXED, __HIP_MEMORY_SCOPE_AGENT) < target)
      __builtin_amdgcn_s_sleep(1);
  }
  __syncthreads();
  asm volatile("" ::: "memory");
}

// ---------------- prep: gathers + bf16 conversions ----------------
__global__ void prep_kernel(const int* __restrict__ src, const int* __restrict__ tgt,
                            const float* __restrict__ enc_emb, const float* __restrict__ dec_emb,
                            const float* __restrict__ enc_Wih, const float* __restrict__ dec_Wih,
                            const float* __restrict__ attn_W, const float* __restrict__ out_W,
                            u16* __restrict__ A_enc, u16* __restrict__ A_dec,
                            u16* __restrict__ WihE, u16* __restrict__ WihD,
                            u16* __restrict__ Web, u16* __restrict__ outWb)
{
  const long n_outw = (long)V_ * H_;
  const long n_aenc = (long)B_ * SSRC * E_;
  const long n_adec = (long)B_ * STGT * E_;
  const long n_wih  = (long)G4 * E_;
  const long n_web  = (long)H_ * H_;
  const long total = n_outw + n_aenc + n_adec + 2 * n_wih + n_web;
  for (long i = (long)blockIdx.x * blockDim.x + threadIdx.x; i < total;
       i += (long)gridDim.x * blockDim.x) {
    long x = i;
    if (x < n_outw) { outWb[x] = f2b(out_W[x]); continue; }
    x -= n_outw;
    if (x < n_aenc) {
      int row = (int)(x >> 8), e = (int)(x & 255);
      A_enc[x] = f2b(enc_emb[(size_t)src[row] * E_ + e]);
      continue;
    }
    x -= n_aenc;
    if (x < n_adec) {
      int row = (int)(x >> 8), e = (int)(x & 255);
      A_dec[x] = f2b(dec_emb[(size_t)tgt[row] * E_ + e]);
      continue;
    }
    x -= n_adec;
    if (x < n_wih) { WihE[x] = f2b(enc_Wih[x]); continue; }
    x -= n_wih;
    if (x < n_wih) {
      int r = (int)(x >> 8), e = (int)(x & 255);
      WihD[x] = f2b(dec_Wih[(size_t)r * 768 + e]);
      continue;
    }
    x -= n_wih;
    {
      int d = (int)(x >> 9), k = (int)(x & 511);
      Web[x] = f2b(attn_W[(size_t)d * 1024 + 512 + k]);
    }
  }
}

// ---------------- NT GEMM: C[m][n] = sum_k A[m][k]*B[n][k] + bias[n] ----------------
template<int KTOT, bool OBF>
__global__ __launch_bounds__(256, 2) void gemm_nt(
    const u16* __restrict__ A, const u16* __restrict__ Bm,
    const float* __restrict__ bias, void* __restrict__ Cv, int M, int N)
{
  int nbm = M >> 7;
  int bn = blockIdx.x / nbm;
  int bm = blockIdx.x % nbm;
  int w = threadIdx.x >> 6, l = threadIdx.x & 63;
  int wr = w >> 1, wc = w & 1;
  int m0 = bm * 128 + wr * 64, n0 = bn * 128 + wc * 64;
  int lr = l & 15, ko = (l >> 4) * 8;
  f32x4 acc[4][4] = {};
  const u16* Ap = A + (size_t)(m0 + lr) * KTOT + ko;
  const u16* Bp = Bm + (size_t)(n0 + lr) * KTOT + ko;
  for (int k0 = 0; k0 < KTOT; k0 += 32) {
    bf16x8 af[4], bfr[4];
#pragma unroll
    for (int i = 0; i < 4; ++i) af[i] = *(const bf16x8*)(Ap + (size_t)i * 16 * KTOT + k0);
#pragma unroll
    for (int i = 0; i < 4; ++i) bfr[i] = *(const bf16x8*)(Bp + (size_t)i * 16 * KTOT + k0);
#pragma unroll
    for (int i = 0; i < 4; ++i)
#pragma unroll
      for (int j = 0; j < 4; ++j)
        acc[i][j] = __builtin_amdgcn_mfma_f32_16x16x32_bf16(af[i], bfr[j], acc[i][j], 0, 0, 0);
  }
  int rbase = (l >> 4) * 4;
#pragma unroll
  for (int i = 0; i < 4; ++i) {
#pragma unroll
    for (int j = 0; j < 4; ++j) {
      int gn = n0 + j * 16 + lr;
      float bv = bias ? bias[gn] : 0.f;
#pragma unroll
      for (int r = 0; r < 4; ++r) {
        int gm = m0 + i * 16 + rbase + r;
        float v = acc[i][j][r] + bv;
        if (OBF) ((u16*)Cv)[(size_t)gm * N + gn] = f2b(v);
        else     ((float*)Cv)[(size_t)gm * N + gn] = v;
      }
    }
  }
}

// ---------------- encoder: persistent, 8 groups x 32 blocks ----------------
__global__ __launch_bounds__(256, 1) void encoder_kernel(
    const float* __restrict__ enc_Whh, const u16* __restrict__ encXW,
    unsigned* __restrict__ h16buf /* u32 [2][32][256] */,
    float* __restrict__ cfin, u16* __restrict__ eo_g, int* __restrict__ bars)
{
  const int tid = threadIdx.x;
  const int g = blockIdx.x & 7;
  const int gb = blockIdx.x >> 3;
  const int b0 = g * 4;
  const int ds0 = gb * 16;
  int* flags = bars + g * 64;
  int ep_ = 0;

  __shared__ float encW[64 * 512];     // f32 [k4][64][4], 128 KB
  __shared__ __align__(16) float hlf[4][H_];
  __shared__ float part[4][256];
  __shared__ float zx[4][64];
  __shared__ float cS[4][16];
  __shared__ float hnS[4][16];

  if (tid < 64) cS[tid >> 4][tid & 15] = 0.f;
  for (int idx = tid; idx < 64 * 512; idx += 256) {
    int row_l = idx >> 9, kk = idx & 511;
    int grow = (row_l >> 4) * 512 + ds0 + (row_l & 15);
    encW[(kk >> 2) * 256 + row_l * 4 + (kk & 3)] = enc_Whh[(size_t)grow * 512 + kk];
  }
  __syncthreads();

  for (int t = 0; t < SSRC; ++t) {
    // stage h (bf16, coherent dwordx4: 256 req)
    {
      const uint4* hb = (const uint4*)(h16buf + (size_t)(t & 1) * 8192) + (size_t)b0 * 64 + tid;
      uint4 v = cload4(hb);
      int row = tid >> 6, c8 = tid & 63;
      float* hp = &hlf[row][c8 * 8];
      hp[0] = b2f((u16)(v.x & 0xffff)); hp[1] = b2f((u16)(v.x >> 16));
      hp[2] = b2f((u16)(v.y & 0xffff)); hp[3] = b2f((u16)(v.y >> 16));
      hp[4] = b2f((u16)(v.z & 0xffff)); hp[5] = b2f((u16)(v.z >> 16));
      hp[6] = b2f((u16)(v.w & 0xffff)); hp[7] = b2f((u16)(v.w >> 16));
    }
    __syncthreads();
    // z = encXW + h @ Whh^T (own 64 gate-rows x 4 b)
    {
      int rl = tid & 63, kq = tid >> 6;
      float acc0 = 0.f, acc1 = 0.f, acc2 = 0.f, acc3 = 0.f;
      int c0 = kq * 32;
#pragma unroll 4
      for (int c = 0; c < 32; ++c) {
        int k4 = c0 + c;
        float4 wv = *(const float4*)&encW[k4 * 256 + rl * 4];
        const float* h0p = &hlf[0][k4 * 4];
        const float* h1p = &hlf[1][k4 * 4];
        const float* h2p = &hlf[2][k4 * 4];
        const float* h3p = &hlf[3][k4 * 4];
        acc0 += wv.x * h0p[0] + wv.y * h0p[1] + wv.z * h0p[2] + wv.w * h0p[3];
        acc1 += wv.x * h1p[0] + wv.y * h1p[1] + wv.z * h1p[2] + wv.w * h1p[3];
        acc2 += wv.x * h2p[0] + wv.y * h2p[1] + wv.z * h2p[2] + wv.w * h2p[3];
        acc3 += wv.x * h3p[0] + wv.y * h3p[1] + wv.z * h3p[2] + wv.w * h3p[3];
      }
      part[kq][0 * 64 + rl] = acc0;
      part[kq][1 * 64 + rl] = acc1;
      part[kq][2 * 64 + rl] = acc2;
      part[kq][3 * 64 + rl] = acc3;
    }
    __syncthreads();
    {
      int b_l = tid >> 6, rl2 = tid & 63;
      float z = part[0][b_l * 64 + rl2] + part[1][b_l * 64 + rl2] +
                part[2][b_l * 64 + rl2] + part[3][b_l * 64 + rl2];
      int grow = (rl2 >> 4) * 512 + ds0 + (rl2 & 15);
      z += b2f(encXW[((size_t)(b0 + b_l) * SSRC + t) * G4 + grow]);
      zx[b_l][rl2] = z;
    }
    __syncthreads();
    if (tid < 64) {
      int bl = tid >> 4, jl = tid & 15;
      int b = b0 + bl, j = ds0 + jl;
      float iv = zx[bl][jl], fv = zx[bl][16 + jl], gv = zx[bl][32 + jl], ov = zx[bl][48 + jl];
      float co = cS[bl][jl];
      float cn = sigm(fv) * co + sigm(iv) * tanh_(gv);
      float hn = sigm(ov) * tanh_(cn);
      cS[bl][jl] = cn;
      hnS[bl][jl] = hn;
      eo_g[((size_t)b * SSRC + t) * H_ + j] = f2b(hn);
    }
    __syncthreads();
    if (tid < 32) {
      int row = tid >> 3, pr = tid & 7;
      unsigned pk = (unsigned)f2b(hnS[row][pr * 2]) | (((unsigned)f2b(hnS[row][pr * 2 + 1])) << 16);
      cstoreu(h16buf + (size_t)((t + 1) & 1) * 8192 + (size_t)(b0 + row) * 256 + gb * 8 + pr, pk);
    }
    gbar(flags, gb, ++ep_);
  }
  if (tid < 64)
    cfin[(size_t)(b0 + (tid >> 4)) * H_ + ds0 + (tid & 15)] = cS[tid >> 4][tid & 15];
}

// ---------------- decoder: persistent, 8 groups x 32 blocks, 4 light phases ------
__global__ __launch_bounds__(256, 1) void decoder_kernel(
    const float* __restrict__ dec_Whh, const float* __restrict__ dec_Wih,
    const float* __restrict__ attn_W, const float* __restrict__ attn_b,
    const float* __restrict__ attn_v,
    const u16* __restrict__ eprojb, const u16* __restrict__ decXW,
    const u16* __restrict__ eo_g,
    unsigned* __restrict__ hd16 /* u32 [32][256] = h16buf[0] */,
    const float* __restrict__ cfin,
    float* __restrict__ vpart /* [8][512][32] */, float* __restrict__ scoreb /* [8][4][128] */,
    unsigned* __restrict__ ctxg /* [8][4][256] */,
    u16* __restrict__ dech, int* __restrict__ bars)
{
  const int tid = threadIdx.x;
  const int g = blockIdx.x & 7;
  const int gb = blockIdx.x >> 3;
  const int b0 = g * 4;
  const int ds0 = gb * 16;
  int* flags = bars + g * 64;
  int ep_ = 0;

  __shared__ u16 decW[2][64 * 512];               // bf16 [k8][64][8], 128 KB
  __shared__ __align__(16) float hlf[4][H_];      // 8 KB
  __shared__ __align__(16) unsigned hl16[4][256]; // 4 KB (raw bf16 pairs)
  __shared__ __align__(16) unsigned cxl16[4][256];
  __shared__ float part[4][256];
  __shared__ float scoreS[4][128];
  __shared__ float aS[4][128];
  __shared__ float zx[4][64];
  __shared__ float qS[4][16], cS[4][16], hnS[4][16], ctxS[4][16];
  __shared__ float vS[16], bS[16];

  if (tid < 64) cS[tid >> 4][tid & 15] = cfin[(size_t)(b0 + (tid >> 4)) * H_ + ds0 + (tid & 15)];
  if (tid < 16) { vS[tid] = attn_v[ds0 + tid]; bS[tid] = attn_b[ds0 + tid]; }
  for (int idx = tid; idx < 64 * 512; idx += 256) {
    int row_l = idx >> 9, kk = idx & 511;
    int grow = (row_l >> 4) * 512 + ds0 + (row_l & 15);
    decW[0][(kk >> 3) * 512 + row_l * 8 + (kk & 7)] = f2b(dec_Whh[(size_t)grow * 512 + kk]);
    decW[1][(kk >> 3) * 512 + row_l * 8 + (kk & 7)] = f2b(dec_Wih[(size_t)grow * 768 + 256 + kk]);
  }
  __syncthreads();

  for (int t = 0; t < STGT; ++t) {
    // ---- Phase A: stage h (256 req); q-slice; energy partials for own d-slice ----
    {
      uint4 v = cload4((const uint4*)hd16 + (size_t)b0 * 64 + tid);
      int row = tid >> 6, c8 = tid & 63;
      ((uint4*)&hl16[row][0])[c8] = v;
      float* hp = &hlf[row][c8 * 8];
      hp[0] = b2f((u16)(v.x & 0xffff)); hp[1] = b2f((u16)(v.x >> 16));
      hp[2] = b2f((u16)(v.y & 0xffff)); hp[3] = b2f((u16)(v.y >> 16));
      hp[4] = b2f((u16)(v.z & 0xffff)); hp[5] = b2f((u16)(v.z >> 16));
      hp[6] = b2f((u16)(v.w & 0xffff)); hp[7] = b2f((u16)(v.w >> 16));
    }
    __syncthreads();
    {
      int b_l = tid >> 6, d_l = (tid >> 2) & 15, kq = tid & 3;
      const float* wrow = attn_W + (size_t)(ds0 + d_l) * 1024;  // W_h row
      float acc = 0.f;
#pragma unroll 8
      for (int kk = kq * 128; kk < kq * 128 + 128; kk += 4) {
        float4 wv = *(const float4*)(wrow + kk);
        const float* hp = &hlf[b_l][kk];
        acc += wv.x * hp[0] + wv.y * hp[1] + wv.z * hp[2] + wv.w * hp[3];
      }
      part[kq][b_l * 16 + d_l] = acc;
    }
    __syncthreads();
    if (tid < 64) {
      int bl = tid >> 4, dl = tid & 15;
      qS[bl][dl] = part[0][bl * 16 + dl] + part[1][bl * 16 + dl] +
                   part[2][bl * 16 + dl] + part[3][bl * 16 + dl] + bS[dl];
    }
    __syncthreads();
#pragma unroll
    for (int r = 0; r < 2; ++r) {
      int idx = tid + r * 256;
      int b_l = idx >> 7, s = idx & 127;
      const uint4* ep = (const uint4*)(eprojb + ((size_t)(b0 + b_l) * SSRC + s) * H_ + ds0);
      uint4 e0 = ep[0], e1 = ep[1];
      float acc = 0.f;
      acc += vS[0]  * tanh_(b2f((u16)(e0.x & 0xffff)) + qS[b_l][0]);
      acc += vS[1]  * tanh_(b2f((u16)(e0.x >> 16))    + qS[b_l][1]);
      acc += vS[2]  * tanh_(b2f((u16)(e0.y & 0xffff)) + qS[b_l][2]);
      acc += vS[3]  * tanh_(b2f((u16)(e0.y >> 16))    + qS[b_l][3]);
      acc += vS[4]  * tanh_(b2f((u16)(e0.z & 0xffff)) + qS[b_l][4]);
      acc += vS[5]  * tanh_(b2f((u16)(e0.z >> 16))    + qS[b_l][5]);
      acc += vS[6]  * tanh_(b2f((u16)(e0.w & 0xffff)) + qS[b_l][6]);
      acc += vS[7]  * tanh_(b2f((u16)(e0.w >> 16))    + qS[b_l][7]);
      acc += vS[8]  * tanh_(b2f((u16)(e1.x & 0xffff)) + qS[b_l][8]);
      acc += vS[9]  * tanh_(b2f((u16)(e1.x >> 16))    + qS[b_l][9]);
      acc += vS[10] * tanh_(b2f((u16)(e1.y & 0xffff)) + qS[b_l][10]);
      acc += vS[11] * tanh_(b2f((u16)(e1.y >> 16))    + qS[b_l][11]);
      acc += vS[12] * tanh_(b2f((u16)(e1.z & 0xffff)) + qS[b_l][12]);
      acc += vS[13] * tanh_(b2f((u16)(e1.z >> 16))    + qS[b_l][13]);
      acc += vS[14] * tanh_(b2f((u16)(e1.w & 0xffff)) + qS[b_l][14]);
      acc += vS[15] * tanh_(b2f((u16)(e1.w >> 16))    + qS[b_l][15]);
      cstoref(vpart + ((size_t)g * 512 + idx) * 32 + gb, acc);
    }
    gbar(flags, gb, ++ep_);

    // ---- Phase B: reduce own s-slice (128 req), publish scores ----
    if (tid < 128) {
      int il = tid >> 3, q8 = tid & 7;
      int b_l = il >> 2, s_l = il & 3;
      int idx = b_l * 128 + gb * 4 + s_l;
      uint4 vv = cload4(vpart + ((size_t)g * 512 + idx) * 32 + q8 * 4);
      float4 f = *(float4*)&vv;
      float sum = f.x + f.y + f.z + f.w;
      sum += __shfl_xor(sum, 1);
      sum += __shfl_xor(sum, 2);
      sum += __shfl_xor(sum, 4);
      if (q8 == 0) cstoref(scoreb + (size_t)(g * 4 + b_l) * 128 + gb * 4 + s_l, sum);
    }
    gbar(flags, gb, ++ep_);

    // ---- Phase C: read scores (128 req), redundant softmax, context d-slice ----
    if (tid < 128) {
      int row = tid >> 5, c4 = tid & 31;
      uint4 vv = cload4(scoreb + (size_t)(g * 4 + row) * 128 + c4 * 4);
      *(float4*)&scoreS[row][c4 * 4] = *(float4*)&vv;
    }
    __syncthreads();
    {
      int w = tid >> 6, lane = tid & 63;
      float s1 = scoreS[w][lane], s2v = scoreS[w][64 + lane];
      float m = fmaxf(s1, s2v);
#pragma unroll
      for (int off = 32; off; off >>= 1) m = fmaxf(m, __shfl_xor(m, off));
      float e1 = __expf(s1 - m), e2 = __expf(s2v - m);
      float sm = e1 + e2;
#pragma unroll
      for (int off = 32; off; off >>= 1) sm += __shfl_xor(sm, off);
      float inv = 1.0f / sm;
      aS[w][lane] = e1 * inv;
      aS[w][64 + lane] = e2 * inv;
    }
    __syncthreads();
    {
      int sq = tid >> 6, b_l = (tid >> 4) & 3, d_l = tid & 15;
      const u16* eo = eo_g + (size_t)(b0 + b_l) * SSRC * H_ + ds0 + d_l;
      float acc = 0.f;
      for (int s = sq * 32; s < sq * 32 + 32; ++s)
        acc += aS[b_l][s] * b2f(eo[(size_t)s * H_]);
      part[sq][b_l * 16 + d_l] = acc;
    }
    __syncthreads();
    if (tid < 64) {
      int bl = tid >> 4, dl = tid & 15;
      ctxS[bl][dl] = part[0][bl * 16 + dl] + part[1][bl * 16 + dl] +
                     part[2][bl * 16 + dl] + part[3][bl * 16 + dl];
    }
    __syncthreads();
    if (tid < 32) {
      int row = tid >> 3, pr = tid & 7;
      unsigned pk = (unsigned)f2b(ctxS[row][pr * 2]) | (((unsigned)f2b(ctxS[row][pr * 2 + 1])) << 16);
      cstoreu(ctxg + (size_t)(g * 4 + row) * 256 + gb * 8 + pr, pk);
    }
    gbar(flags, gb, ++ep_);

    // ---- Phase D: stage ctx (256 req); z = Whh@h + WihC@ctx (bf16 dot2); gates ----
    {
      uint4 v = cload4((const uint4*)ctxg + (size_t)g * 256 + tid);
      int row = tid >> 6, c4 = tid & 63;
      ((uint4*)&cxl16[row][0])[c4] = v;
    }
    __syncthreads();
    {
      int rl = tid & 63, kq = tid >> 6;
      float acc0 = 0.f, acc1 = 0.f, acc2 = 0.f, acc3 = 0.f;
      const uint4* W0 = (const uint4*)&decW[0][0];
      const uint4* W1 = (const uint4*)&decW[1][0];
#pragma unroll 2
      for (int k8 = kq * 16; k8 < kq * 16 + 16; ++k8) {
        uint4 w0 = W0[k8 * 64 + rl];
        uint4 w1 = W1[k8 * 64 + rl];
        uint4 h0 = ((const uint4*)&hl16[0][0])[k8];
        uint4 x0 = ((const uint4*)&cxl16[0][0])[k8];
        acc0 = dot2u(w0.x, h0.x, dot2u(w0.y, h0.y, dot2u(w0.z, h0.z, dot2u(w0.w, h0.w, acc0))));
        acc0 = dot2u(w1.x, x0.x, dot2u(w1.y, x0.y, dot2u(w1.z, x0.z, dot2u(w1.w, x0.w, acc0))));
        uint4 h1 = ((const uint4*)&hl16[1][0])[k8];
        uint4 x1 = ((const uint4*)&cxl16[1][0])[k8];
        acc1 = dot2u(w0.x, h1.x, dot2u(w0.y, h1.y, dot2u(w0.z, h1.z, dot2u(w0.w, h1.w, acc1))));
        acc1 = dot2u(w1.x, x1.x, dot2u(w1.y, x1.y, dot2u(w1.z, x1.z, dot2u(w1.w, x1.w, acc1))));
        uint4 h2 = ((const uint4*)&hl16[2][0])[k8];
        uint4 x2 = ((const uint4*)&cxl16[2][0])[k8];
        acc2 = dot2u(w0.x, h2.x, dot2u(w0.y, h2.y, dot2u(w0.z, h2.z, dot2u(w0.w, h2.w, acc2))));
        acc2 = dot2u(w1.x, x2.x, dot2u(w1.y, x2.y, dot2u(w1.z, x2.z, dot2u(w1.w, x2.w, acc2))));
        uint4 h3 = ((const uint4*)&hl16[3][0])[k8];
        uint4 x3 = ((const uint4*)&cxl16[3][0])[k8];
        acc3 = dot2u(w0.x, h3.x, dot2u(w0.y, h3.y, dot2u(w0.z, h3.z, dot2u(w0.w, h3.w, acc3))));
        acc3 = dot2u(w1.x, x3.x, dot2u(w1.y, x3.y, dot2u(w1.z, x3.z, dot2u(w1.w, x3.w, acc3))));
      }
      part[kq][0 * 64 + rl] = acc0;
      part[kq][1 * 64 + rl] = acc1;
      part[kq][2 * 64 + rl] = acc2;
      part[kq][3 * 64 + rl] = acc3;
    }
    __syncthreads();
    {
      int b_l = tid >> 6, rl2 = tid & 63;
      float z = part[0][b_l * 64 + rl2] + part[1][b_l * 64 + rl2] +
                part[2][b_l * 64 + rl2] + part[3][b_l * 64 + rl2];
      int grow = (rl2 >> 4) * 512 + ds0 + (rl2 & 15);
      z += b2f(decXW[((size_t)(b0 + b_l) * STGT + t) * G4 + grow]);
      zx[b_l][rl2] = z;
    }
    __syncthreads();
    if (tid < 64) {
      int bl = tid >> 4, jl = tid & 15;
      int b = b0 + bl, j = ds0 + jl;
      float iv = zx[bl][jl], fv = zx[bl][16 + jl], gv = zx[bl][32 + jl], ov = zx[bl][48 + jl];
      float co = cS[bl][jl];
      float cn = sigm(fv) * co + sigm(iv) * tanh_(gv);
      float hn = sigm(ov) * tanh_(cn);
      cS[bl][jl] = cn;
      hnS[bl][jl] = hn;
      dech[((size_t)b * STGT + t) * H_ + j] = f2b(hn);
    }
    __syncthreads();
    if (tid < 32) {
      int row = tid >> 3, pr = tid & 7;
      unsigned pk = (unsigned)f2b(hnS[row][pr * 2]) | (((unsigned)f2b(hnS[row][pr * 2 + 1])) << 16);
      cstoreu(hd16 + (size_t)(b0 + row) * 256 + gb * 8 + pr, pk);
    }
    gbar(flags, gb, ++ep_);
  }
}

// ---------------- workspace layout (bytes) ----------------
#define OFF_BARE   0u
#define OFF_BARD   2048u
#define OFF_H16    4096u        // u32 [2][32][256] = 64 KB
#define OFF_CFIN   69632u       // f32 [32][512] = 64 KB
#define OFF_SCORE  135168u      // f32 [8][4][128] = 16 KB
#define OFF_CTXG   151552u      // u32 [8][4][256] = 32 KB
#define OFF_VPART  184320u      // f32 [8][512][32] = 512 KB
#define OFF_AENC   1048576u     // 2 MB
#define OFF_ADEC   3145728u     // 1 MB
#define OFF_WIHE   4194304u     // 1 MB
#define OFF_WIHD   5242880u     // 1 MB
#define OFF_WEB    6291456u     // 512 KB
#define OFF_OUTW   6815744u     // 32.77 MB
#define OFF_ENCXW  39583744u    // 16.78 MB
#define OFF_DECXW  56360960u    // 8.39 MB
#define OFF_EO     64749568u    // 4.19 MB
#define OFF_EPROJ  68943872u    // 4.19 MB
#define OFF_DECH   73138176u    // 2.10 MB -> end 75.2 MB

extern "C" void kernel_launch(void* const* d_in, const int* in_sizes, int n_in,
                              void* d_out, int out_size, void* d_ws, size_t ws_size,
                              hipStream_t stream)
{
  const int*   src     = (const int*)d_in[0];
  const int*   tgt     = (const int*)d_in[1];
  const float* enc_emb = (const float*)d_in[2];
  const float* enc_Wih = (const float*)d_in[3];
  const float* enc_Whh = (const float*)d_in[4];
  const float* enc_b   = (const float*)d_in[5];
  const float* attn_W  = (const float*)d_in[6];
  const float* attn_b  = (const float*)d_in[7];
  const float* attn_v  = (const float*)d_in[8];
  const float* dec_emb = (const float*)d_in[9];
  const float* dec_Wih = (const float*)d_in[10];
  const float* dec_Whh = (const float*)d_in[11];
  const float* dec_b   = (const float*)d_in[12];
  const float* out_W   = (const float*)d_in[13];
  const float* out_b   = (const float*)d_in[14];

  char* ws = (char*)d_ws;
  int*      barE   = (int*)(ws + OFF_BARE);
  int*      barD   = (int*)(ws + OFF_BARD);
  unsigned* h16buf = (unsigned*)(ws + OFF_H16);
  float*    cfin   = (float*)(ws + OFF_CFIN);
  float*    scoreb = (float*)(ws + OFF_SCORE);
  unsigned* ctxg   = (unsigned*)(ws + OFF_CTXG);
  float*    vpart  = (float*)(ws + OFF_VPART);
  u16*      A_enc  = (u16*)(ws + OFF_AENC);
  u16*      A_dec  = (u16*)(ws + OFF_ADEC);
  u16*      WihE   = (u16*)(ws + OFF_WIHE);
  u16*      WihD   = (u16*)(ws + OFF_WIHD);
  u16*      Web    = (u16*)(ws + OFF_WEB);
  u16*      outWb  = (u16*)(ws + OFF_OUTW);
  u16*      encXW  = (u16*)(ws + OFF_ENCXW);
  u16*      decXW  = (u16*)(ws + OFF_DECXW);
  u16*      eo_g   = (u16*)(ws + OFF_EO);
  u16*      eprojb = (u16*)(ws + OFF_EPROJ);
  u16*      dech   = (u16*)(ws + OFF_DECH);

  // zero barriers + h buffers (h16buf both halves)
  hipMemsetAsync(d_ws, 0, OFF_H16 + 65536, stream);

  prep_kernel<<<2048, 256, 0, stream>>>(src, tgt, enc_emb, dec_emb, enc_Wih, dec_Wih,
                                        attn_W, out_W, A_enc, A_dec, WihE, WihD, Web, outWb);

  // encXW = emb_src @ enc_Wih^T + enc_b   (4096 x 2048 x 256) -> bf16
  gemm_nt<256, true><<<512, 256, 0, stream>>>(A_enc, WihE, enc_b, (void*)encXW, 4096, 2048);
  // decXW = emb_tgt @ dec_Wih[:, :E]^T + dec_b  (2048 x 2048 x 256) -> bf16
  gemm_nt<256, true><<<256, 256, 0, stream>>>(A_dec, WihD, dec_b, (void*)decXW, 2048, 2048);

  encoder_kernel<<<256, 256, 0, stream>>>(enc_Whh, encXW, h16buf, cfin, eo_g, barE);

  // enc_proj = enc_out @ W_e^T  (4096 x 512 x 512) -> bf16
  gemm_nt<512, true><<<128, 256, 0, stream>>>(eo_g, Web, nullptr, (void*)eprojb, 4096, 512);

  decoder_kernel<<<256, 256, 0, stream>>>(dec_Whh, dec_Wih, attn_W, attn_b, attn_v,
                                          eprojb, decXW, eo_g, h16buf, cfin,
                                          vpart, scoreb, ctxg, dech, barD);

  // out = dec_h @ out_W^T + out_b  (2048 x 32000 x 512) -> f32
  gemm_nt<512, false><<<4000, 256, 0, stream>>>(dech, outWb, out_b, d_out, 2048, 32000);
}

// Round 7
// 1555.130 us; speedup vs baseline: 10.7542x; 1.4483x over previous
//
#include <hip/hip_runtime.h>

#define B_    32
#define SSRC  128
#define STGT  64
#define E_    256
#define H_    512
#define G4    2048
#define V_    32000

typedef unsigned short u16;
typedef short bf16x8 __attribute__((ext_vector_type(8)));
typedef float f32x4 __attribute__((ext_vector_type(4)));

__device__ __forceinline__ u16 f2b(float f) {
  unsigned u = __float_as_uint(f);
  u += 0x7FFFu + ((u >> 16) & 1u);
  return (u16)(u >> 16);
}
__device__ __forceinline__ float b2f(u16 h) {
  return __uint_as_float(((unsigned)h) << 16);
}
__device__ __forceinline__ unsigned pk2(float lo, float hi) {
  return (unsigned)f2b(lo) | (((unsigned)f2b(hi)) << 16);
}
__device__ __forceinline__ float sigm(float x) { return 1.0f / (1.0f + __expf(-x)); }
__device__ __forceinline__ float tanh_(float x) { return 1.0f - 2.0f / (1.0f + __expf(2.0f * x)); }

// ---- packed bf16x2 dot ----
#if defined(__has_builtin)
#if __has_builtin(__builtin_amdgcn_fdot2_f32_bf16)
#define HAS_DOT2 1
#endif
#endif
#ifdef HAS_DOT2
typedef __bf16 b162 __attribute__((ext_vector_type(2)));
__device__ __forceinline__ float dot2u(unsigned a, unsigned b, float acc) {
  return __builtin_amdgcn_fdot2_f32_bf16(__builtin_bit_cast(b162, a),
                                         __builtin_bit_cast(b162, b), acc, false);
}
#else
__device__ __forceinline__ float dot2u(unsigned a, unsigned b, float acc) {
  acc += __uint_as_float(a << 16) * __uint_as_float(b << 16);
  acc += __uint_as_float(a & 0xffff0000u) * __uint_as_float(b & 0xffff0000u);
  return acc;
}
#endif
__device__ __forceinline__ float dot4(uint4 w, uint4 h, float acc) {
  return dot2u(w.w, h.w, dot2u(w.z, h.z, dot2u(w.y, h.y, dot2u(w.x, h.x, acc))));
}

// XOR swizzle for [*][64-uint4] LDS rows: spreads 64B-strided k-chunks across banks
__device__ __forceinline__ int swz64(int c) {
  return (c & ~3) | ((c & 3) ^ ((c >> 3) & 3));
}

// ---- device-coherent accesses (global sc0 sc1), no whole-cache maintenance ----
__device__ __forceinline__ uint4 cload4(const void* p) {
  uint4 r;
  asm volatile("global_load_dwordx4 %0, %1, off sc0 sc1\n\ts_waitcnt vmcnt(0)"
               : "=&v"(r) : "v"(p) : "memory");
  return r;
}
__device__ __forceinline__ void cload4x2(uint4& a, uint4& b, const void* pa, const void* pb) {
  asm volatile("global_load_dwordx4 %0, %2, off sc0 sc1\n\t"
               "global_load_dwordx4 %1, %3, off sc0 sc1\n\t"
               "s_waitcnt vmcnt(0)"
               : "=&v"(a), "=&v"(b) : "v"(pa), "v"(pb) : "memory");
}
__device__ __forceinline__ void cstoreu(unsigned* p, unsigned v) {
  asm volatile("global_store_dword %0, %1, off sc0 sc1" :: "v"(p), "v"(v) : "memory");
}
// 128-bit asm INPUT operands unsupported (round-6 compile fail) -> 4 dword stores
__device__ __forceinline__ void cstore4(unsigned* p, uint4 v) {
  cstoreu(p + 0, v.x);
  cstoreu(p + 1, v.y);
  cstoreu(p + 2, v.z);
  cstoreu(p + 3, v.w);
}

// ---- group barrier: per-block flag + gang poll, no cache-maintenance fences ----
__device__ __forceinline__ void gbar(int* flags, int myid, int target) {
  asm volatile("s_waitcnt vmcnt(0)" ::: "memory");
  __syncthreads();
  if (threadIdx.x == 0)
    __hip_atomic_store(flags + myid, target, __ATOMIC_RELAXED, __HIP_MEMORY_SCOPE_AGENT);
  if (threadIdx.x < 64) {
    int l = threadIdx.x & 31;
    while (__hip_atomic_load(flags + l, __ATOMIC_RELAXED, __HIP_MEMORY_SCOPE_AGENT) < target)
      __builtin_amdgcn_s_sleep(1);
  }
  __syncthreads();
  asm volatile("" ::: "memory");
}

// ---------------- prep: gathers + bf16 conversions ----------------
__global__ void prep_kernel(const int* __restrict__ src, const int* __restrict__ tgt,
                            const float* __restrict__ enc_emb, const float* __restrict__ dec_emb,
                            const float* __restrict__ enc_Wih, const float* __restrict__ dec_Wih,
                            const float* __restrict__ attn_W, const float* __restrict__ out_W,
                            u16* __restrict__ A_enc, u16* __restrict__ A_dec,
                            u16* __restrict__ WihE, u16* __restrict__ WihD,
                            u16* __restrict__ Web, u16* __restrict__ WihCp,
                            u16* __restrict__ outWb)
{
  const long n_outw = (long)V_ * H_;
  const long n_aenc = (long)B_ * SSRC * E_;
  const long n_adec = (long)B_ * STGT * E_;
  const long n_wih  = (long)G4 * E_;
  const long n_web  = (long)H_ * H_;
  const long n_wcp  = (long)G4 * H_;
  const long total = n_outw + n_aenc + n_adec + 2 * n_wih + n_web + n_wcp;
  for (long i = (long)blockIdx.x * blockDim.x + threadIdx.x; i < total;
       i += (long)gridDim.x * blockDim.x) {
    long x = i;
    if (x < n_outw) { outWb[x] = f2b(out_W[x]); continue; }
    x -= n_outw;
    if (x < n_aenc) {
      int row = (int)(x >> 8), e = (int)(x & 255);
      A_enc[x] = f2b(enc_emb[(size_t)src[row] * E_ + e]);
      continue;
    }
    x -= n_aenc;
    if (x < n_adec) {
      int row = (int)(x >> 8), e = (int)(x & 255);
      A_dec[x] = f2b(dec_emb[(size_t)tgt[row] * E_ + e]);
      continue;
    }
    x -= n_adec;
    if (x < n_wih) { WihE[x] = f2b(enc_Wih[x]); continue; }
    x -= n_wih;
    if (x < n_wih) {
      int r = (int)(x >> 8), e = (int)(x & 255);
      WihD[x] = f2b(dec_Wih[(size_t)r * 768 + e]);
      continue;
    }
    x -= n_wih;
    if (x < n_web) {
      int d = (int)(x >> 9), k = (int)(x & 511);
      Web[x] = f2b(attn_W[(size_t)d * 1024 + 512 + k]);
      continue;
    }
    x -= n_web;
    {
      // permuted WihC rows: n = gb*64 + gate*16 + jl  ->  orig gate*512 + gb*16 + jl
      int n = (int)(x >> 9), k = (int)(x & 511);
      int gb = n >> 6, gate = (n >> 4) & 3, jl = n & 15;
      int orig = gate * 512 + gb * 16 + jl;
      WihCp[x] = f2b(dec_Wih[(size_t)orig * 768 + 256 + k]);
    }
  }
}

// ---------------- NT GEMM: C[m][n] = sum_k A[m][k]*B[n][k] + bias[n] ----------------
template<int KTOT, bool OBF>
__global__ __launch_bounds__(256, 2) void gemm_nt(
    const u16* __restrict__ A, const u16* __restrict__ Bm,
    const float* __restrict__ bias, void* __restrict__ Cv, int M, int N)
{
  int nbm = M >> 7;
  int bn = blockIdx.x / nbm;
  int bm = blockIdx.x % nbm;
  int w = threadIdx.x >> 6, l = threadIdx.x & 63;
  int wr = w >> 1, wc = w & 1;
  int m0 = bm * 128 + wr * 64, n0 = bn * 128 + wc * 64;
  int lr = l & 15, ko = (l >> 4) * 8;
  f32x4 acc[4][4] = {};
  const u16* Ap = A + (size_t)(m0 + lr) * KTOT + ko;
  const u16* Bp = Bm + (size_t)(n0 + lr) * KTOT + ko;
  for (int k0 = 0; k0 < KTOT; k0 += 32) {
    bf16x8 af[4], bfr[4];
#pragma unroll
    for (int i = 0; i < 4; ++i) af[i] = *(const bf16x8*)(Ap + (size_t)i * 16 * KTOT + k0);
#pragma unroll
    for (int i = 0; i < 4; ++i) bfr[i] = *(const bf16x8*)(Bp + (size_t)i * 16 * KTOT + k0);
#pragma unroll
    for (int i = 0; i < 4; ++i)
#pragma unroll
      for (int j = 0; j < 4; ++j)
        acc[i][j] = __builtin_amdgcn_mfma_f32_16x16x32_bf16(af[i], bfr[j], acc[i][j], 0, 0, 0);
  }
  int rbase = (l >> 4) * 4;
#pragma unroll
  for (int i = 0; i < 4; ++i) {
#pragma unroll
    for (int j = 0; j < 4; ++j) {
      int gn = n0 + j * 16 + lr;
      float bv = bias ? bias[gn] : 0.f;
#pragma unroll
      for (int r = 0; r < 4; ++r) {
        int gm = m0 + i * 16 + rbase + r;
        float v = acc[i][j][r] + bv;
        if (OBF) ((u16*)Cv)[(size_t)gm * N + gn] = f2b(v);
        else     ((float*)Cv)[(size_t)gm * N + gn] = v;
      }
    }
  }
}

// ---- shared z-GEMV: 64 gate-rows x 512 k, bf16, swizzled LDS ----
__device__ __forceinline__ void zgemv64(int tid, const uint4* Wu, const uint4* Hu,
                                        float (*part)[64][4]) {
  int rq = tid >> 4, kq = tid & 15;
  float acc[4][4] = {};
#pragma unroll
  for (int u = 0; u < 4; ++u) {
    int sc = swz64(kq * 4 + u);
    uint4 h0 = Hu[sc], h1 = Hu[64 + sc], h2 = Hu[128 + sc], h3 = Hu[192 + sc];
#pragma unroll
    for (int r = 0; r < 4; ++r) {
      uint4 wv = Wu[(rq * 4 + r) * 64 + sc];
      acc[r][0] = dot4(wv, h0, acc[r][0]);
      acc[r][1] = dot4(wv, h1, acc[r][1]);
      acc[r][2] = dot4(wv, h2, acc[r][2]);
      acc[r][3] = dot4(wv, h3, acc[r][3]);
    }
  }
#pragma unroll
  for (int r = 0; r < 4; ++r) {
    float4 v = {acc[r][0], acc[r][1], acc[r][2], acc[r][3]};
    *(float4*)&part[kq][(rq * 4 + r) ^ (kq & 7)][0] = v;
  }
}

// ---- LDS weight fill from f32 global (64 rows x 512 k), swizzled ----
template<typename GrowF>
__device__ __forceinline__ void fillw64(int tid, const float* Wsrc, uint4* Wu, GrowF grow) {
#pragma unroll 4
  for (int i = 0; i < 16; ++i) {
    int idx4 = tid + i * 256;
    int row = idx4 >> 6, c = idx4 & 63;
    const float* s = Wsrc + (size_t)grow(row) * 512 + c * 8;
    float4 a = *(const float4*)s, b4 = *(const float4*)(s + 4);
    uint4 pkv = {pk2(a.x, a.y), pk2(a.z, a.w), pk2(b4.x, b4.y), pk2(b4.z, b4.w)};
    Wu[row * 64 + swz64(c)] = pkv;
  }
}

// ---------------- encoder: persistent, 8 groups x 32 blocks ----------------
__global__ __launch_bounds__(256, 1) void encoder_kernel(
    const float* __restrict__ enc_Whh, const u16* __restrict__ encXW,
    unsigned* __restrict__ h16buf /* u32 [2][32][256] */,
    float* __restrict__ cfin, u16* __restrict__ eo_g, int* __restrict__ bars)
{
  const int tid = threadIdx.x;
  const int g = blockIdx.x & 7;
  const int gb = blockIdx.x >> 3;
  const int b0 = g * 4;
  const int ds0 = gb * 16;
  int* flags = bars + g * 64;
  int ep_ = 0;

  __shared__ uint4 encW4[64 * 64];          // 64 KB bf16 Whh slice
  __shared__ uint4 hl16[4 * 64];            // 4 KB h (bf16 pairs), swizzled
  __shared__ float part[16][64][4];         // 16 KB
  __shared__ float zx[4][64];
  __shared__ float cS[4][16];

  if (tid < 64) cS[tid >> 4][tid & 15] = 0.f;
  fillw64(tid, enc_Whh, encW4, [&](int row) { return (row >> 4) * 512 + ds0 + (row & 15); });
  __syncthreads();

  for (int t = 0; t < SSRC; ++t) {
    // stage h (coherent, 1 dwordx4/thread)
    {
      int row = tid >> 6, c = tid & 63;
      uint4 v = cload4((const uint4*)h16buf + (size_t)(t & 1) * 2048 + (b0 + row) * 64 + c);
      hl16[row * 64 + swz64(c)] = v;
    }
    __syncthreads();
    zgemv64(tid, encW4, hl16, part);
    __syncthreads();
    // combine + encXW
    {
      int b_l = tid >> 6, rl = tid & 63;
      float z = 0.f;
#pragma unroll
      for (int kq = 0; kq < 16; ++kq) z += part[kq][rl ^ (kq & 7)][b_l];
      int grow = (rl >> 4) * 512 + ds0 + (rl & 15);
      z += b2f(encXW[((size_t)(b0 + b_l) * SSRC + t) * G4 + grow]);
      zx[b_l][rl] = z;
    }
    __syncthreads();
    if (tid < 64) {
      int bl = tid >> 4, jl = tid & 15;
      float iv = zx[bl][jl], fv = zx[bl][16 + jl], gv = zx[bl][32 + jl], ov = zx[bl][48 + jl];
      float cn = sigm(fv) * cS[bl][jl] + sigm(iv) * tanh_(gv);
      float hn = sigm(ov) * tanh_(cn);
      cS[bl][jl] = cn;
      eo_g[((size_t)(b0 + bl) * SSRC + t) * H_ + ds0 + jl] = f2b(hn);
      float hn1 = __shfl_down(hn, 1);
      if ((jl & 1) == 0)
        cstoreu(h16buf + (size_t)((t + 1) & 1) * 8192 + (size_t)(b0 + bl) * 256 + gb * 8 + (jl >> 1),
                pk2(hn, hn1));
    }
    gbar(flags, gb, ++ep_);
  }
  if (tid < 64)
    cfin[(size_t)(b0 + (tid >> 4)) * H_ + ds0 + (tid & 15)] = cS[tid >> 4][tid & 15];
}

// ---------------- decoder: persistent, 8 groups x 32 blocks, 3 phases ------------
__global__ __launch_bounds__(256, 1) void decoder_kernel(
    const float* __restrict__ dec_Whh, const float* __restrict__ attn_W,
    const float* __restrict__ attn_b, const float* __restrict__ attn_v,
    const u16* __restrict__ eprojb, const u16* __restrict__ decXW,
    const u16* __restrict__ eoPb,
    unsigned* __restrict__ hd16 /* u32 [32][256] */, const float* __restrict__ cfin,
    float* __restrict__ qg /* f32 [8][4][512] */, float* __restrict__ scoreb /* [8][4][128] */,
    u16* __restrict__ dech, int* __restrict__ bars)
{
  const int tid = threadIdx.x;
  const int g = blockIdx.x & 7;
  const int gb = blockIdx.x >> 3;
  const int b0 = g * 4;
  const int ds0 = gb * 16;
  int* flags = bars + g * 64;
  int ep_ = 0;

  __shared__ uint4 decW4[64 * 64];          // 64 KB Whh slice
  __shared__ uint4 Whb4[16 * 64];           // 16 KB W_h rows (d-slice), row-XOR swz
  __shared__ uint4 hl16[4 * 64];            // 4 KB
  __shared__ float part[16][64][4];         // 16 KB (Whh partials)
  __shared__ float partE[8][64][4];         // 8 KB (eoP partials)
  __shared__ float4 qf4[4 * 128];           // 8 KB q full (swizzled)
  __shared__ float4 vf4[128];               // 2 KB attn_v (swizzled)
  __shared__ float scoreS[4][128];
  __shared__ float aS[4][128];
  __shared__ float zx[4][64];
  __shared__ __align__(16) float qS[4][16];
  __shared__ __align__(16) float scr16[4][4];
  __shared__ float cS[4][16];
  __shared__ float bS[16];

  if (tid < 64) cS[tid >> 4][tid & 15] = cfin[(size_t)(b0 + (tid >> 4)) * H_ + ds0 + (tid & 15)];
  if (tid < 16) bS[tid] = attn_b[ds0 + tid];
  if (tid < 128) {
    float4 v = *(const float4*)(attn_v + tid * 4);
    vf4[tid ^ ((tid >> 3) & 7)] = v;
  }
  fillw64(tid, dec_Whh, decW4, [&](int row) { return (row >> 4) * 512 + ds0 + (row & 15); });
  // Whb: 16 rows x 512 k from attn_W[:, :512]
#pragma unroll
  for (int i = 0; i < 4; ++i) {
    int idx4 = tid + i * 256;
    int row = idx4 >> 6, c = idx4 & 63;
    const float* s = attn_W + (size_t)(ds0 + row) * 1024 + c * 8;
    float4 a = *(const float4*)s, b4 = *(const float4*)(s + 4);
    uint4 pkv = {pk2(a.x, a.y), pk2(a.z, a.w), pk2(b4.x, b4.y), pk2(b4.z, b4.w)};
    Whb4[row * 64 + (c ^ (row & 7))] = pkv;
  }
  __syncthreads();

  for (int t = 0; t < STGT; ++t) {
    // ---- Phase A: stage h; q-slice (16 d); publish q ----
    {
      int row = tid >> 6, c = tid & 63;
      uint4 v = cload4((const uint4*)hd16 + (b0 + row) * 64 + c);
      hl16[row * 64 + swz64(c)] = v;
    }
    __syncthreads();
    {
      int b_l = tid >> 6, d_l = (tid >> 2) & 15, kq4 = tid & 3;
      float acc = 0.f;
#pragma unroll
      for (int u = 0; u < 16; ++u) {
        int c = kq4 * 16 + u;
        uint4 wv = Whb4[d_l * 64 + (c ^ (d_l & 7))];
        uint4 hv = hl16[b_l * 64 + swz64(c)];
        acc = dot4(wv, hv, acc);
      }
      acc += __shfl_xor(acc, 1);
      acc += __shfl_xor(acc, 2);
      if (kq4 == 0) qS[b_l][d_l] = acc + bS[d_l];
    }
    __syncthreads();
    if (tid < 16) {
      float4 v = *(float4*)&qS[tid >> 2][(tid & 3) * 4];
      cstore4((unsigned*)(qg + (size_t)(g * 4 + (tid >> 2)) * 512 + ds0 + (tid & 3) * 4),
              *(uint4*)&v);
    }
    gbar(flags, gb, ++ep_);

    // ---- Phase B: read q full; energies for own 4-s slice over all 512 d ----
    {
      int b_l = tid >> 6, c = tid & 63;
      uint4 a, b4;
      const float* sp = qg + (size_t)(g * 4 + b_l) * 512 + c * 8;
      cload4x2(a, b4, sp, sp + 4);
      int lw0 = c * 2, lw1 = c * 2 + 1;
      qf4[b_l * 128 + (lw0 ^ ((lw0 >> 3) & 7))] = *(float4*)&a;
      qf4[b_l * 128 + (lw1 ^ ((lw1 >> 3) & 7))] = *(float4*)&b4;
    }
    __syncthreads();
    {
      int p = tid >> 4, lane16 = tid & 15;
      int b_l = p >> 2, s_l = p & 3;
      int s = gb * 4 + s_l;
      const uint4* ep = (const uint4*)(eprojb + ((size_t)(b0 + b_l) * SSRC + s) * H_) + lane16 * 4;
      uint4 e0 = ep[0], e1 = ep[1], e2 = ep[2], e3 = ep[3];
      unsigned ev[8] = {e0.x, e0.y, e0.z, e0.w, e1.x, e1.y, e1.z, e1.w};
      unsigned ev2[8] = {e2.x, e2.y, e2.z, e2.w, e3.x, e3.y, e3.z, e3.w};
      float acc = 0.f;
#pragma unroll
      for (int i = 0; i < 8; ++i) {
        int lr = lane16 * 8 + i;
        float4 q = qf4[b_l * 128 + (lr ^ ((lr >> 3) & 7))];
        float4 vv = vf4[lr ^ ((lr >> 3) & 7)];
        unsigned lo = (i < 4) ? ev[i * 2] : ev2[(i - 4) * 2];
        unsigned hi = (i < 4) ? ev[i * 2 + 1] : ev2[(i - 4) * 2 + 1];
        acc += vv.x * tanh_(b2f((u16)(lo & 0xffff)) + q.x);
        acc += vv.y * tanh_(b2f((u16)(lo >> 16)) + q.y);
        acc += vv.z * tanh_(b2f((u16)(hi & 0xffff)) + q.z);
        acc += vv.w * tanh_(b2f((u16)(hi >> 16)) + q.w);
      }
      acc += __shfl_xor(acc, 1);
      acc += __shfl_xor(acc, 2);
      acc += __shfl_xor(acc, 4);
      acc += __shfl_xor(acc, 8);
      if (lane16 == 0) scr16[b_l][s_l] = acc;
    }
    __syncthreads();
    if (tid < 4) {
      float4 v = *(float4*)&scr16[tid][0];
      cstore4((unsigned*)(scoreb + (size_t)(g * 4 + tid) * 128 + gb * 4), *(uint4*)&v);
    }
    gbar(flags, gb, ++ep_);

    // ---- Phase C: scores->softmax; z = Whh@h + sum_s a*eoP + decXW; gates ----
    if (tid < 128) {
      int row = tid >> 5, c4 = tid & 31;
      uint4 vv = cload4(scoreb + (size_t)(g * 4 + row) * 128 + c4 * 4);
      *(float4*)&scoreS[row][c4 * 4] = *(float4*)&vv;
    }
    zgemv64(tid, decW4, hl16, part);
    __syncthreads();
    {
      int w = tid >> 6, lane = tid & 63;
      float s1 = scoreS[w][lane], s2v = scoreS[w][64 + lane];
      float m = fmaxf(s1, s2v);
#pragma unroll
      for (int off = 32; off; off >>= 1) m = fmaxf(m, __shfl_xor(m, off));
      float e1 = __expf(s1 - m), e2 = __expf(s2v - m);
      float sm = e1 + e2;
#pragma unroll
      for (int off = 32; off; off >>= 1) sm += __shfl_xor(sm, off);
      float inv = 1.0f / sm;
      aS[w][lane] = e1 * inv;
      aS[w][64 + lane] = e2 * inv;
    }
    __syncthreads();
    // eoP partials: thread (sq = tid>>5, cp = tid&31): cols cp*2, cp*2+1
    {
      int sq = tid >> 5, cp = tid & 31;
      const unsigned* eoPu = (const unsigned*)eoPb;
      float a0 = 0.f, a1 = 0.f, a2 = 0.f, a3 = 0.f, a4 = 0.f, a5 = 0.f, a6 = 0.f, a7 = 0.f;
#pragma unroll 4
      for (int s = sq * 16; s < sq * 16 + 16; ++s) {
        unsigned u0 = eoPu[((size_t)(b0 + 0) * SSRC + s) * 1024 + gb * 32 + cp];
        unsigned u1 = eoPu[((size_t)(b0 + 1) * SSRC + s) * 1024 + gb * 32 + cp];
        unsigned u2 = eoPu[((size_t)(b0 + 2) * SSRC + s) * 1024 + gb * 32 + cp];
        unsigned u3 = eoPu[((size_t)(b0 + 3) * SSRC + s) * 1024 + gb * 32 + cp];
        float w0 = aS[0][s], w1 = aS[1][s], w2 = aS[2][s], w3 = aS[3][s];
        a0 += w0 * b2f((u16)(u0 & 0xffff)); a1 += w0 * b2f((u16)(u0 >> 16));
        a2 += w1 * b2f((u16)(u1 & 0xffff)); a3 += w1 * b2f((u16)(u1 >> 16));
        a4 += w2 * b2f((u16)(u2 & 0xffff)); a5 += w2 * b2f((u16)(u2 >> 16));
        a6 += w3 * b2f((u16)(u3 & 0xffff)); a7 += w3 * b2f((u16)(u3 >> 16));
      }
      float4 lo = {a0, a2, a4, a6}, hi = {a1, a3, a5, a7};
      *(float4*)&partE[sq][cp * 2][0] = lo;
      *(float4*)&partE[sq][cp * 2 + 1][0] = hi;
    }
    __syncthreads();
    {
      int b_l = tid >> 6, rl = tid & 63;
      float z = 0.f;
#pragma unroll
      for (int kq = 0; kq < 16; ++kq) z += part[kq][rl ^ (kq & 7)][b_l];
#pragma unroll
      for (int sq = 0; sq < 8; ++sq) z += partE[sq][rl][b_l];
      int grow = (rl >> 4) * 512 + ds0 + (rl & 15);
      z += b2f(decXW[((size_t)(b0 + b_l) * STGT + t) * G4 + grow]);
      zx[b_l][rl] = z;
    }
    __syncthreads();
    if (tid < 64) {
      int bl = tid >> 4, jl = tid & 15;
      float iv = zx[bl][jl], fv = zx[bl][16 + jl], gv = zx[bl][32 + jl], ov = zx[bl][48 + jl];
      float cn = sigm(fv) * cS[bl][jl] + sigm(iv) * tanh_(gv);
      float hn = sigm(ov) * tanh_(cn);
      cS[bl][jl] = cn;
      dech[((size_t)(b0 + bl) * STGT + t) * H_ + ds0 + jl] = f2b(hn);
      float hn1 = __shfl_down(hn, 1);
      if ((jl & 1) == 0)
        cstoreu(hd16 + (size_t)(b0 + bl) * 256 + gb * 8 + (jl >> 1), pk2(hn, hn1));
    }
    gbar(flags, gb, ++ep_);
  }
}

// ---------------- workspace layout (bytes) ----------------
#define OFF_BARE   0u
#define OFF_BARD   2048u
#define OFF_H16    4096u        // u32 [2][32][256] = 64 KB
#define OFF_CFIN   69632u       // 64 KB
#define OFF_QG     135168u      // f32 [8][4][512] = 64 KB
#define OFF_SCORE  200704u      // 16 KB
#define OFF_AENC   262144u      // 2 MB
#define OFF_ADEC   2359296u     // 1 MB
#define OFF_WIHE   3407872u     // 1 MB
#define OFF_WIHD   4456448u     // 1 MB
#define OFF_WEB    5505024u     // 512 KB
#define OFF_WIHCP  6029312u     // 2 MB
#define OFF_OUTW   8126464u     // 32.77 MB
#define OFF_ENCXW  40894464u    // 16.78 MB  [aliased by eoP after encoder]
#define OFF_DECXW  57671680u    // 8.39 MB
#define OFF_EO     66060288u    // 4.19 MB
#define OFF_EPROJ  70254592u    // 4.19 MB
#define OFF_DECH   74448896u    // 2.10 MB -> end 76.5 MB

extern "C" void kernel_launch(void* const* d_in, const int* in_sizes, int n_in,
                              void* d_out, int out_size, void* d_ws, size_t ws_size,
                              hipStream_t stream)
{
  const int*   src     = (const int*)d_in[0];
  const int*   tgt     = (const int*)d_in[1];
  const float* enc_emb = (const float*)d_in[2];
  const float* enc_Wih = (const float*)d_in[3];
  const float* enc_Whh = (const float*)d_in[4];
  const float* enc_b   = (const float*)d_in[5];
  const float* attn_W  = (const float*)d_in[6];
  const float* attn_b  = (const float*)d_in[7];
  const float* attn_v  = (const float*)d_in[8];
  const float* dec_emb = (const float*)d_in[9];
  const float* dec_Wih = (const float*)d_in[10];
  const float* dec_Whh = (const float*)d_in[11];
  const float* dec_b   = (const float*)d_in[12];
  const float* out_W   = (const float*)d_in[13];
  const float* out_b   = (const float*)d_in[14];

  char* ws = (char*)d_ws;
  int*      barE   = (int*)(ws + OFF_BARE);
  int*      barD   = (int*)(ws + OFF_BARD);
  unsigned* h16buf = (unsigned*)(ws + OFF_H16);
  float*    cfin   = (float*)(ws + OFF_CFIN);
  float*    qg     = (float*)(ws + OFF_QG);
  float*    scoreb = (float*)(ws + OFF_SCORE);
  u16*      A_enc  = (u16*)(ws + OFF_AENC);
  u16*      A_dec  = (u16*)(ws + OFF_ADEC);
  u16*      WihE   = (u16*)(ws + OFF_WIHE);
  u16*      WihD   = (u16*)(ws + OFF_WIHD);
  u16*      Web    = (u16*)(ws + OFF_WEB);
  u16*      WihCp  = (u16*)(ws + OFF_WIHCP);
  u16*      outWb  = (u16*)(ws + OFF_OUTW);
  u16*      encXW  = (u16*)(ws + OFF_ENCXW);
  u16*      eoPb   = (u16*)(ws + OFF_ENCXW);   // alias: encXW dead after encoder
  u16*      decXW  = (u16*)(ws + OFF_DECXW);
  u16*      eo_g   = (u16*)(ws + OFF_EO);
  u16*      eprojb = (u16*)(ws + OFF_EPROJ);
  u16*      dech   = (u16*)(ws + OFF_DECH);

  // zero barriers + h buffers
  (void)hipMemsetAsync(d_ws, 0, OFF_H16 + 65536, stream);

  prep_kernel<<<2048, 256, 0, stream>>>(src, tgt, enc_emb, dec_emb, enc_Wih, dec_Wih,
                                        attn_W, out_W, A_enc, A_dec, WihE, WihD, Web, WihCp, outWb);

  // encXW = emb_src @ enc_Wih^T + enc_b   (4096 x 2048 x 256) -> bf16
  gemm_nt<256, true><<<512, 256, 0, stream>>>(A_enc, WihE, enc_b, (void*)encXW, 4096, 2048);
  // decXW = emb_tgt @ dec_Wih[:, :E]^T + dec_b  (2048 x 2048 x 256) -> bf16
  gemm_nt<256, true><<<256, 256, 0, stream>>>(A_dec, WihD, dec_b, (void*)decXW, 2048, 2048);

  encoder_kernel<<<256, 256, 0, stream>>>(enc_Whh, encXW, h16buf, cfin, eo_g, barE);

  // eproj = enc_out @ W_e^T  (4096 x 512 x 512) -> bf16
  gemm_nt<512, true><<<128, 256, 0, stream>>>(eo_g, Web, nullptr, (void*)eprojb, 4096, 512);
  // eoP = enc_out @ WihCp^T  (4096 x 2048 x 512) -> bf16  (overwrites encXW)
  gemm_nt<512, true><<<512, 256, 0, stream>>>(eo_g, WihCp, nullptr, (void*)eoPb, 4096, 2048);

  decoder_kernel<<<256, 256, 0, stream>>>(dec_Whh, attn_W, attn_b, attn_v,
                                          eprojb, decXW, eoPb, h16buf, cfin,
                                          qg, scoreb, dech, barD);

  // out = dec_h @ out_W^T + out_b  (2048 x 32000 x 512) -> f32
  gemm_nt<512, false><<<4000, 256, 0, stream>>>(dech, outWb, out_b, d_out, 2048, 32000);
}